// Round 7
// baseline (201.896 us; speedup 1.0000x reference)
//
#include <hip/hip_runtime.h>
#include <hip/hip_bf16.h>
#include <math.h>

// ws layout (float slots)
#define OFF_XH   0UL         // bf16 x  (bh, l, 128)
#define OFF_XT   1572864UL   // bf16 x^T (bh, 128, l) token-paired u32
#define OFF_VC   3145728UL   // bf16 vc (b, l, 768)
#define OFF_SQ   4718592UL   // fp32 per-(bh,l) sumsq          (24576)
#define OFF_PART 4767744UL   // fp32 partials: [0..3071] V-sum (bh,tg:S1,S2); [4096..4863] dist (bh,iq:D1,D2)
#define OFF_ACC  4780056UL   // 336
#define OFF_CTR  4780392UL   // 1 uint (k5b6 completion counter)
#define OFF_FCWB 4780396UL   // bf16 fcW cast, 21*768 (8064 u16)

typedef __attribute__((ext_vector_type(8))) __bf16 bf16x8;
typedef __attribute__((ext_vector_type(4))) float f32x4;
typedef __attribute__((ext_vector_type(8))) unsigned short u16x8;

// ---------------- K1: pure gather -> xh, xT, sq + per-(bh,tg) V-sum partials ----------------
// 1536 blocks x 256 thr (bh, 16-token group). No dist, no big LDS -> high occupancy, gather once.
__global__ __launch_bounds__(256) void k1_gather(const int* __restrict__ tids,
    const float* __restrict__ TF, const float* __restrict__ DF,
    const float* __restrict__ emb, unsigned short* __restrict__ xh,
    unsigned short* __restrict__ xT, float* __restrict__ sq, float* __restrict__ part,
    const float* __restrict__ fcW, unsigned short* __restrict__ fcWb,
    float* __restrict__ acc, unsigned int* __restrict__ ctr) {
  int bid = blockIdx.x;
  int bh = bid >> 4, tg = bid & 15;
  int b = bh / 6, h = bh % 6;
  int T0 = tg * 16;
  int tid = threadIdx.x;
  __shared__ float swgt[16];
  __shared__ int stid[16];
  __shared__ unsigned short tT[128][18];
  __shared__ float srs1[16], srs2[16];
  if (bid == 0) {                          // zero acc + k5b6 counter (256-thread block!)
    for (int i = tid; i < 336; i += 256) acc[i] = 0.0f;
    if (tid == 0) *ctr = 0u;
  }
  if (tg == 1 && tid < 168) {              // fcW -> bf16 cast over the 96 tg==1 blocks
    int i2 = bh * 168 + tid;
    fcWb[i2] = __bfloat16_as_ushort(__float2bfloat16(fcW[i2]));
  }
  if (tid < 16) {
    int tok = b * 256 + T0 + tid;
    stid[tid] = tids[tok];
    swgt[tid] = fminf(TF[tok], 20.0f) * log1pf(1.0f / DF[tok]);
  }
  __syncthreads();
  int r = tid >> 4, c8 = (tid & 15) * 8;
  const float* er = emb + (size_t)stid[r] * 768 + h * 128 + c8;
  float wgt = swgt[r];
  float4 e0 = *(const float4*)er;
  float4 e1 = *(const float4*)(er + 4);
  float f[8] = {e0.x, e0.y, e0.z, e0.w, e1.x, e1.y, e1.z, e1.w};
  float s1 = 0.0f, s2 = 0.0f;
  u16x8 pk;
#pragma unroll
  for (int e = 0; e < 8; ++e) {
    __hip_bfloat16 hb = __float2bfloat16(f[e] * wgt);
    float g = __bfloat162float(hb);
    s1 += g; s2 += g * g;
    pk[e] = __bfloat16_as_ushort(hb);
  }
  *(u16x8*)(xh + ((size_t)(bh * 256 + T0 + r)) * 128 + c8) = pk;
  s1 += __shfl_down(s1, 8); s1 += __shfl_down(s1, 4);
  s1 += __shfl_down(s1, 2); s1 += __shfl_down(s1, 1);
  s2 += __shfl_down(s2, 8); s2 += __shfl_down(s2, 4);
  s2 += __shfl_down(s2, 2); s2 += __shfl_down(s2, 1);
  if ((tid & 15) == 0) {
    sq[(size_t)bh * 256 + T0 + r] = s2;
    srs1[r] = s1; srs2[r] = s2;
  }
#pragma unroll
  for (int j = 0; j < 8; ++j) tT[c8 + j][r] = pk[j];
  __syncthreads();
  if (tid == 0) {
    float v1 = 0.0f, v2 = 0.0f;
#pragma unroll
    for (int i = 0; i < 16; ++i) { v1 += srs1[i]; v2 += srs2[i]; }
    part[((size_t)bh * 16 + tg) * 2 + 0] = v1;
    part[((size_t)bh * 16 + tg) * 2 + 1] = v2;
  }
  int ch = tid >> 1, half = tid & 1;
  unsigned int* xo = (unsigned int*)xT + ((size_t)(bh * 128 + ch)) * 128 + tg * 8 + half * 4;
#pragma unroll
  for (int k = 0; k < 4; ++k)
    xo[k] = *(const unsigned int*)&tT[ch][(half * 4 + k) * 2];
}

// ---------------- K2: dist-BN partials straight from xh (L2), no LDS tile ----------------
// 384 blocks x 512 thr, XCD-pinned (same bh map as k45). Wave w -> i-tile iq*4+(w>>1), j-half w&1.
__global__ __launch_bounds__(512) void k2_dist(const unsigned short* __restrict__ xh,
    const float* __restrict__ sq, float* __restrict__ part) {
  int bid = blockIdx.x;
  int xcd = bid & 7, idx = bid >> 3;       // 48 blocks per XCD
  int bh = xcd * 12 + idx % 12;            // matches k45's bh->XCD map
  int iq = idx / 12;                       // 0..3: i-tile quarter
  int tid = threadIdx.x, w = tid >> 6, lane = tid & 63;
  int quad = lane >> 4, l16 = lane & 15;
  int it = iq * 4 + (w >> 1), jh = w & 1;
  __shared__ float swd1[8], swd2[8];
  const __bf16* xb = (const __bf16*)xh + (size_t)bh * 256 * 128;
  const float* sqh = sq + (size_t)bh * 256;
  bf16x8 a[4];
#pragma unroll
  for (int k0 = 0; k0 < 4; ++k0)
    a[k0] = *(const bf16x8*)(xb + (size_t)(it * 16 + l16) * 128 + k0 * 32 + quad * 8);
  float si[4];
#pragma unroll
  for (int r = 0; r < 4; ++r) si[r] = sqh[it * 16 + quad * 4 + r];
  float ls1 = 0.0f, ls2 = 0.0f;
#pragma unroll
  for (int jt = 0; jt < 8; ++jt) {
    int j0 = jh * 128 + jt * 16;
    f32x4 acc = {0.0f, 0.0f, 0.0f, 0.0f};
#pragma unroll
    for (int k0 = 0; k0 < 4; ++k0) {
      bf16x8 bfr = *(const bf16x8*)(xb + (size_t)(j0 + l16) * 128 + k0 * 32 + quad * 8);
      acc = __builtin_amdgcn_mfma_f32_16x16x32_bf16(a[k0], bfr, acc, 0, 0, 0);
    }
    float sj = sqh[j0 + l16];
#pragma unroll
    for (int r = 0; r < 4; ++r) {
      float cv = sqrtf(fmaxf(si[r] + sj - 2.0f * acc[r], 1e-12f));
      ls1 += cv; ls2 += cv * cv;
    }
  }
#pragma unroll
  for (int off = 32; off >= 1; off >>= 1) {
    ls1 += __shfl_down(ls1, off);
    ls2 += __shfl_down(ls2, off);
  }
  if (lane == 0) { swd1[w] = ls1; swd2[w] = ls2; }
  __syncthreads();
  if (tid == 0) {
    float d1 = 0.0f, d2 = 0.0f;
#pragma unroll
    for (int i = 0; i < 8; ++i) { d1 += swd1[i]; d2 += swd2[i]; }
    part[4096 + (bh * 4 + iq) * 2 + 0] = d1;
    part[4096 + (bh * 4 + iq) * 2 + 1] = d2;
  }
}

// ---------------- K45: stats finalize + dist+bn+leaky+mask+softmax (LDS co) + AV ----------------
// 1D grid 1536, XCD-aware: all 16 p-blocks of a bh land on the XCD that produced xh/xT(bh).
__global__ __launch_bounds__(256, 4) void k45_fused(const unsigned short* __restrict__ xh,
    const unsigned short* __restrict__ xT, const int* __restrict__ tids,
    const float* __restrict__ sq, const float* __restrict__ part,
    unsigned short* __restrict__ vc16) {
  int bid = blockIdx.x;
  int xcd = bid & 7, idx = bid >> 3;
  int bh = xcd * 12 + idx % 12;            // 96 bh / 8 XCDs = 12 each
  int p = idx / 12;
  int b = bh / 6, h = bh % 6;
  int tid = threadIdx.x, w = tid >> 6, lane = tid & 63;
  int quad = lane >> 4, l16 = lane & 15;
  int I = p * 16;
  __shared__ float svld[256];
  __shared__ float ssq[256];
  __shared__ unsigned short cot[16][264];
  __shared__ float smax[16][4];
  __shared__ float ssum[16][4];
  __shared__ float sstat[4];               // m, rsc, mv, rvs
  svld[tid] = (tids[b * 256 + tid] != 0) ? 1.0f : 0.0f;
  ssq[tid] = sq[(size_t)bh * 256 + tid];
  if (w == 0) {                            // finalize BN stats from k1/k2 partials (this h only)
    float c1 = 0.0f, c2 = 0.0f;
    {
      int bb = lane >> 2, jj = lane & 3;   // 16 b x 4 iq = 64 lanes
      c1 = part[4096 + ((bb * 6 + h) * 4 + jj) * 2 + 0];
      c2 = part[4096 + ((bb * 6 + h) * 4 + jj) * 2 + 1];
    }
    float v1 = 0.0f, v2 = 0.0f;
#pragma unroll
    for (int t = 0; t < 4; ++t) {          // 16 b x 16 tg = 256 partials, 4 per lane
      int g = lane * 4 + t;
      int b2 = g >> 4, tg2 = g & 15;
      v1 += part[((size_t)(b2 * 6 + h) * 16 + tg2) * 2 + 0];
      v2 += part[((size_t)(b2 * 6 + h) * 16 + tg2) * 2 + 1];
    }
#pragma unroll
    for (int off = 32; off >= 1; off >>= 1) {
      c1 += __shfl_down(c1, off);
      c2 += __shfl_down(c2, off);
      v1 += __shfl_down(v1, off);
      v2 += __shfl_down(v2, off);
    }
    if (lane == 0) {
      float mean = c1 / 1048576.0f;                    // B*L*L
      float var = c2 / 1048576.0f - mean * mean;
      sstat[0] = mean;
      sstat[1] = rsqrtf(var + 1e-5f);
      float mv = v1 / 524288.0f;                       // B*L*dh
      float vv = v2 / 524288.0f - mv * mv;
      sstat[2] = mv;
      sstat[3] = rsqrtf(vv + 1e-5f);
    }
  }
  const __bf16* xb = (const __bf16*)xh + (size_t)bh * 256 * 128;
  bf16x8 a[4];
#pragma unroll
  for (int k0 = 0; k0 < 4; ++k0)
    a[k0] = *(const bf16x8*)(xb + (size_t)(I + l16) * 128 + k0 * 32 + quad * 8);
  __syncthreads();
  float m = sstat[0], rsc = sstat[1];
  float rv[4], si[4];
#pragma unroll
  for (int r = 0; r < 4; ++r) {
    rv[r] = svld[I + quad * 4 + r];
    si[r] = ssq[I + quad * 4 + r];
  }
  float y[4][4];
#pragma unroll
  for (int tl = 0; tl < 4; ++tl) {
    int t = w * 4 + tl;
    f32x4 acc = {0.0f, 0.0f, 0.0f, 0.0f};
#pragma unroll
    for (int k0 = 0; k0 < 4; ++k0) {
      bf16x8 bfr = *(const bf16x8*)(xb + (size_t)(t * 16 + l16) * 128 + k0 * 32 + quad * 8);
      acc = __builtin_amdgcn_mfma_f32_16x16x32_bf16(a[k0], bfr, acc, 0, 0, 0);
    }
    float sj = ssq[t * 16 + l16];
    float cvld = svld[t * 16 + l16];
#pragma unroll
    for (int r = 0; r < 4; ++r) {
      float cv = sqrtf(fmaxf(si[r] + sj - 2.0f * acc[r], 1e-12f));
      float yv = (cv - m) * rsc;
      yv = yv >= 0.0f ? yv : 9.0f * yv;
      y[tl][r] = yv * rv[r] * cvld;
    }
  }
#pragma unroll
  for (int r = 0; r < 4; ++r) {
    float mx = fmaxf(fmaxf(y[0][r], y[1][r]), fmaxf(y[2][r], y[3][r]));
#pragma unroll
    for (int off = 1; off <= 8; off <<= 1) mx = fmaxf(mx, __shfl_xor(mx, off));
    if (l16 == 0) smax[quad * 4 + r][w] = mx;
  }
  __syncthreads();
  float gmx[4];
#pragma unroll
  for (int r = 0; r < 4; ++r) {
    int row = quad * 4 + r;
    gmx[r] = fmaxf(fmaxf(smax[row][0], smax[row][1]), fmaxf(smax[row][2], smax[row][3]));
    float s = 0.0f;
#pragma unroll
    for (int tl = 0; tl < 4; ++tl) { y[tl][r] = expf(y[tl][r] - gmx[r]); s += y[tl][r]; }
#pragma unroll
    for (int off = 1; off <= 8; off <<= 1) s += __shfl_xor(s, off);
    if (l16 == 0) ssum[row][w] = s;
  }
  __syncthreads();
#pragma unroll
  for (int r = 0; r < 4; ++r) {
    int row = quad * 4 + r;
    float gs = ssum[row][0] + ssum[row][1] + ssum[row][2] + ssum[row][3];
    float inv = 1.0f / gs;
#pragma unroll
    for (int tl = 0; tl < 4; ++tl)
      cot[row][w * 64 + tl * 16 + l16] =
          __bfloat16_as_ushort(__float2bfloat16(y[tl][r] * inv));
  }
  __syncthreads();
  bf16x8 a2[8];
#pragma unroll
  for (int k0 = 0; k0 < 8; ++k0)
    a2[k0] = *(const bf16x8*)&cot[l16][k0 * 32 + quad * 8];
  const __bf16* xbT = (const __bf16*)xT + (size_t)bh * 128 * 256;
  float mv = sstat[2], rvs = sstat[3];
  float rm = rvs * mv;
  size_t vbase = ((size_t)(b * 256 + I + quad * 4)) * 768 + h * 128;
#pragma unroll
  for (int jl = 0; jl < 2; ++jl) {
    int ch = (w * 2 + jl) * 16 + l16;
    const __bf16* brow = xbT + (size_t)ch * 256;
    f32x4 vacc = {0.0f, 0.0f, 0.0f, 0.0f};
#pragma unroll
    for (int k0 = 0; k0 < 8; ++k0) {
      bf16x8 bfr = *(const bf16x8*)(brow + k0 * 32 + quad * 8);
      vacc = __builtin_amdgcn_mfma_f32_16x16x32_bf16(a2[k0], bfr, vacc, 0, 0, 0);
    }
#pragma unroll
    for (int r = 0; r < 4; ++r) {
      float ov = rvs * vacc[r] - rm;
      vc16[vbase + (size_t)r * 768 + ch] = __bfloat16_as_ushort(__float2bfloat16(ov));
    }
  }
}

// ---------------- K5b6: logits via MFMA + 21-softmax + accumulate + last-block final softmax ----------------
// XCD-pinned so each block reads vc(b) from the XCD whose k45 blocks produced it (L2-resident).
__global__ __launch_bounds__(256) void k5b6_lgts(const unsigned short* __restrict__ vc16,
    const unsigned short* __restrict__ fcWb, const float* __restrict__ fcb,
    float* __restrict__ acc, unsigned int* __restrict__ ctr, float* __restrict__ out) {
  int bid = blockIdx.x;
  int xcd = bid & 7, idx = bid >> 3;       // 8 blocks per XCD
  int b = xcd * 2 + (idx & 1);             // matches k45's b->XCD map
  int qa = idx >> 1;
  int tid = threadIdx.x, w = tid >> 6, lane = tid & 63;
  int quad = lane >> 4, l16 = lane & 15;
  int tok0 = b * 256 + qa * 64 + w * 16;
  int c1c = (l16 < 5) ? (16 + l16) : 20;
  const __bf16* vb = (const __bf16*)vc16;
  const __bf16* w0 = (const __bf16*)fcWb + (size_t)l16 * 768;
  const __bf16* w1 = (const __bf16*)fcWb + (size_t)c1c * 768;
  f32x4 ac0 = {0.0f, 0.0f, 0.0f, 0.0f}, ac1 = {0.0f, 0.0f, 0.0f, 0.0f};
#pragma unroll
  for (int k0 = 0; k0 < 24; ++k0) {
    int ko = k0 * 32 + quad * 8;
    bf16x8 af = *(const bf16x8*)(vb + (size_t)(tok0 + l16) * 768 + ko);
    bf16x8 b0 = *(const bf16x8*)(w0 + ko);
    bf16x8 b1 = *(const bf16x8*)(w1 + ko);
    ac0 = __builtin_amdgcn_mfma_f32_16x16x32_bf16(af, b0, ac0, 0, 0, 0);
    ac1 = __builtin_amdgcn_mfma_f32_16x16x32_bf16(af, b1, ac1, 0, 0, 0);
  }
  float bias0 = fcb[l16];
  float bias1 = (l16 < 5) ? fcb[16 + l16] : 0.0f;
  float p0s = 0.0f, p1s = 0.0f;
#pragma unroll
  for (int r = 0; r < 4; ++r) {
    float lg0 = ac0[r] + bias0;
    float lg1 = (l16 < 5) ? (ac1[r] + bias1) : -1e30f;
    float mx = fmaxf(lg0, lg1);
#pragma unroll
    for (int off = 1; off <= 8; off <<= 1) mx = fmaxf(mx, __shfl_xor(mx, off));
    float e0 = expf(lg0 - mx), e1 = expf(lg1 - mx);
    float s = e0 + e1;
#pragma unroll
    for (int off = 1; off <= 8; off <<= 1) s += __shfl_xor(s, off);
    float inv = 1.0f / s;
    p0s += e0 * inv;
    p1s += e1 * inv;
  }
  p0s += __shfl_xor(p0s, 16); p0s += __shfl_xor(p0s, 32);
  p1s += __shfl_xor(p1s, 16); p1s += __shfl_xor(p1s, 32);
  __shared__ float sacc[4][21];
  __shared__ unsigned int sdone;
  if (quad == 0) sacc[w][l16] = p0s;
  if (quad == 1 && l16 < 5) sacc[w][16 + l16] = p1s;
  __syncthreads();
  if (tid < 21) {
    float s = sacc[0][tid] + sacc[1][tid] + sacc[2][tid] + sacc[3][tid];
    atomicAdd(&acc[b * 21 + tid], s);
  }
  __syncthreads();   // barrier drains vmcnt: this block's atomics are globally performed
  if (tid == 0) {
    __threadfence();
    sdone = atomicAdd(ctr, 1u);
  }
  __syncthreads();
  if (sdone == 63u && tid < 16) {
    float v[20];
    float mx = -1e30f;
#pragma unroll
    for (int c = 0; c < 20; ++c) {
      v[c] = atomicAdd(&acc[tid * 21 + c], 0.0f);   // coherent read (XCD-safe)
      mx = fmaxf(mx, v[c]);
    }
    float s = 0.0f;
#pragma unroll
    for (int c = 0; c < 20; ++c) { v[c] = expf(v[c] - mx); s += v[c]; }
    float inv = 1.0f / s;
#pragma unroll
    for (int c = 0; c < 20; ++c) out[tid * 20 + c] = v[c] * inv;
  }
}

extern "C" void kernel_launch(void* const* d_in, const int* in_sizes, int n_in,
                              void* d_out, int out_size, void* d_ws, size_t ws_size,
                              hipStream_t stream) {
  const int*   tids = (const int*)d_in[0];
  const float* TF   = (const float*)d_in[1];
  const float* DF   = (const float*)d_in[2];
  const float* emb  = (const float*)d_in[3];
  const float* fcW  = (const float*)d_in[4];
  const float* fcb  = (const float*)d_in[5];
  // d_in[6]=weiW, d_in[7]=weib: dead code (cw branch is provably all-ones)
  float* out = (float*)d_out;
  float* ws  = (float*)d_ws;
  unsigned short* xh   = (unsigned short*)(ws + OFF_XH);
  unsigned short* xT   = (unsigned short*)(ws + OFF_XT);
  unsigned short* vc   = (unsigned short*)(ws + OFF_VC);
  unsigned short* fcWb = (unsigned short*)(ws + OFF_FCWB);
  float* sq    = ws + OFF_SQ;
  float* part  = ws + OFF_PART;
  float* acc   = ws + OFF_ACC;
  unsigned int* ctr = (unsigned int*)(ws + OFF_CTR);

  k1_gather<<<1536, 256, 0, stream>>>(tids, TF, DF, emb, xh, xT, sq, part,
                                      fcW, fcWb, acc, ctr);
  k2_dist<<<384, 512, 0, stream>>>(xh, sq, part);
  k45_fused<<<1536, 256, 0, stream>>>(xh, xT, tids, sq, part, vc);
  k5b6_lgts<<<64, 256, 0, stream>>>(vc, fcWb, fcb, acc, ctr, out);
}

// Round 8
// 188.035 us; speedup vs baseline: 1.0737x; 1.0737x over previous
//
#include <hip/hip_runtime.h>
#include <hip/hip_bf16.h>
#include <math.h>

// ws layout (float slots)
#define OFF_XH   0UL         // bf16 x  (bh, l, 128)
#define OFF_XT   1572864UL   // bf16 x^T (bh, 128, l) token-paired u32
#define OFF_VC   3145728UL   // bf16 vc (b, l, 768)
#define OFF_SQ   4718592UL   // fp32 per-(bh,l) sumsq          (24576)
#define OFF_PART 4767744UL   // fp32 partials: [0..191] V-sum (bh:S1,S2); [192..959] dist (bh,jq:D1,D2)
#define OFF_ACC  4780056UL   // 336
#define OFF_CTR  4780392UL   // 1 uint (k5b6 completion counter)
#define OFF_FCWB 4780396UL   // bf16 fcW cast, 21*768 (8064 u16)
#define OFF_CV   8388608UL   // fp32 dist matrix (bh, i, j) 96*256*256 = 6291456 (ends at 58.7 MB)

typedef __attribute__((ext_vector_type(8))) __bf16 bf16x8;
typedef __attribute__((ext_vector_type(4))) float f32x4;
typedef __attribute__((ext_vector_type(8))) unsigned short u16x8;

// ---------------- K12: gather -> LDS tile (+xh, xT, sq) + dist (stored fp32) + BN partials ----------------
// 1D grid 384, XCD-pinned: xcd=bid&7, bh=xcd*12+idx%12, jq=idx/12 (4 col-quarters per bh).
// cv is computed ONCE here and stored; k45 reads it instead of recomputing (bit-identical).
__global__ __launch_bounds__(512) void k12_fused(const int* __restrict__ tids,
    const float* __restrict__ TF, const float* __restrict__ DF,
    const float* __restrict__ emb, unsigned short* __restrict__ xh,
    unsigned short* __restrict__ xT, float* __restrict__ sq,
    float* __restrict__ part, const float* __restrict__ fcW,
    unsigned short* __restrict__ fcWb, float* __restrict__ acc,
    unsigned int* __restrict__ ctr, float* __restrict__ cvws) {
  int bid = blockIdx.x;
  int xcd = bid & 7, idx = bid >> 3;       // 48 blocks per XCD
  int bh = xcd * 12 + idx % 12;            // same bh->XCD map as k45 (L2 handoff)
  int jq = idx / 12;                       // 0..3: dist col-quarter
  int b = bh / 6, h = bh % 6;
  int tid = threadIdx.x;
  __shared__ unsigned short tile[32768];   // 64 KiB
  __shared__ float swd1[8], swd2[8], swv1[8], swv2[8];
  if (jq == 1) {                           // fcW -> bf16 cast, partitioned over 96 blocks
    if (tid < 168) {
      int i2 = bh * 168 + tid;
      fcWb[i2] = __bfloat16_as_ushort(__float2bfloat16(fcW[i2]));
    }
  } else if (jq == 0 && bh == 0) {         // zero acc + k5b6 counter (2 launches ahead)
    if (tid < 336) acc[tid] = 0.0f;
    if (tid == 336) *ctr = 0u;
  }
  int sub = tid & 7, row0 = tid >> 3;      // 8 threads per token row
  int c16 = sub * 16;
  float ts1 = 0.0f, ts2 = 0.0f;            // per-thread V-sum partials
#pragma unroll
  for (int p = 0; p < 4; ++p) {
    int r = p * 64 + row0;
    int tok = b * 256 + r;
    int tv = tids[tok];
    float wgt = fminf(TF[tok], 20.0f) * log1pf(1.0f / DF[tok]);
    const float* er = emb + (size_t)tv * 768 + h * 128 + c16;
    float4 e0 = *(const float4*)er;
    float4 e1 = *(const float4*)(er + 4);
    float4 e2 = *(const float4*)(er + 8);
    float4 e3 = *(const float4*)(er + 12);
    float f[16] = {e0.x, e0.y, e0.z, e0.w, e1.x, e1.y, e1.z, e1.w,
                   e2.x, e2.y, e2.z, e2.w, e3.x, e3.y, e3.z, e3.w};
    u16x8 pk0, pk1;
    float s1 = 0.0f, s2 = 0.0f;
#pragma unroll
    for (int e = 0; e < 8; ++e) {
      __hip_bfloat16 hb = __float2bfloat16(f[e] * wgt);
      float g = __bfloat162float(hb);
      s1 += g; s2 += g * g;
      pk0[e] = __bfloat16_as_ushort(hb);
    }
#pragma unroll
    for (int e = 0; e < 8; ++e) {
      __hip_bfloat16 hb = __float2bfloat16(f[8 + e] * wgt);
      float g = __bfloat162float(hb);
      s1 += g; s2 += g * g;
      pk1[e] = __bfloat16_as_ushort(hb);
    }
    ts1 += s1; ts2 += s2;
    int rx = r & 7;
    *(u16x8*)&tile[r * 128 + (((sub * 2    ) ^ rx) * 8)] = pk0;
    *(u16x8*)&tile[r * 128 + (((sub * 2 + 1) ^ rx) * 8)] = pk1;
    if (jq == 0) {   // linear xh for k5b6... (xh now only feeds nothing in k45; kept for layout stability)
      unsigned short* xo = xh + ((size_t)bh * 256 + r) * 128 + c16;
      *(u16x8*)xo = pk0;
      *(u16x8*)(xo + 8) = pk1;
    }
    s2 += __shfl_down(s2, 4); s2 += __shfl_down(s2, 2); s2 += __shfl_down(s2, 1);
    if (sub == 0)
      sq[(size_t)bh * 256 + r] = s2;       // all 4 jq blocks write identical values (benign)
  }
  __syncthreads();
  // jq==3 block emits the channel-major transpose xT (token-paired u32) from LDS
  if (jq == 3) {
    int ch = tid & 127, q = tid >> 7;          // 4 token-quarters
    int cc = ch >> 3, cs = ch & 7;
    unsigned int* xo = (unsigned int*)xT + ((size_t)bh * 128 + ch) * 128 + q * 32;
#pragma unroll
    for (int g = 0; g < 8; ++g) {
      unsigned int tmp[4];
#pragma unroll
      for (int k = 0; k < 4; ++k) {
        int t0 = q * 64 + (g * 4 + k) * 2;
        unsigned int lo = tile[ t0      * 128 + ((cc ^ ( t0      & 7)) * 8) + cs];
        unsigned int hi = tile[(t0 + 1) * 128 + ((cc ^ ((t0 + 1) & 7)) * 8) + cs];
        tmp[k] = lo | (hi << 16);
      }
      uint4 vv; vv.x = tmp[0]; vv.y = tmp[1]; vv.z = tmp[2]; vv.w = tmp[3];
      *(uint4*)(xo + g * 4) = vv;
    }
  }
  // dist: wave w -> i-tiles {2w,2w+1}, cols [64*jq, 64*jq+64); store cv fp32 + BN partials
  int w = tid >> 6, lane = tid & 63, quad = lane >> 4, l16 = lane & 15;
  const float* sqh = sq + (size_t)bh * 256;
  int it0 = w * 2;
  bf16x8 a2[2][4];
  float si2[2][4];
#pragma unroll
  for (int ith = 0; ith < 2; ++ith) {
    int ar = (it0 + ith) * 16 + l16, arx = ar & 7;
#pragma unroll
    for (int k0 = 0; k0 < 4; ++k0)
      a2[ith][k0] = *(const bf16x8*)&tile[ar * 128 + (((k0 * 4 + quad) ^ arx) * 8)];
#pragma unroll
    for (int r = 0; r < 4; ++r)
      si2[ith][r] = sqh[(it0 + ith) * 16 + quad * 4 + r];
  }
  float ls1 = 0.0f, ls2 = 0.0f;
#pragma unroll
  for (int jt = 0; jt < 4; ++jt) {
    int jcol = jq * 64 + jt * 16 + l16;
    int jrx = jcol & 7;
    bf16x8 bfr[4];
#pragma unroll
    for (int k0 = 0; k0 < 4; ++k0)
      bfr[k0] = *(const bf16x8*)&tile[jcol * 128 + (((k0 * 4 + quad) ^ jrx) * 8)];
    f32x4 acc0 = {0.0f, 0.0f, 0.0f, 0.0f}, acc1 = {0.0f, 0.0f, 0.0f, 0.0f};
#pragma unroll
    for (int k0 = 0; k0 < 4; ++k0) {
      acc0 = __builtin_amdgcn_mfma_f32_16x16x32_bf16(a2[0][k0], bfr[k0], acc0, 0, 0, 0);
      acc1 = __builtin_amdgcn_mfma_f32_16x16x32_bf16(a2[1][k0], bfr[k0], acc1, 0, 0, 0);
    }
    float sj = sqh[jcol];
#pragma unroll
    for (int r = 0; r < 4; ++r) {
      float cv0 = sqrtf(fmaxf(si2[0][r] + sj - 2.0f * acc0[r], 1e-12f));
      float cv1 = sqrtf(fmaxf(si2[1][r] + sj - 2.0f * acc1[r], 1e-12f));
      cvws[((size_t)bh * 256 + (it0    ) * 16 + quad * 4 + r) * 256 + jcol] = cv0;
      cvws[((size_t)bh * 256 + (it0 + 1) * 16 + quad * 4 + r) * 256 + jcol] = cv1;
      ls1 += cv0 + cv1;
      ls2 += cv0 * cv0 + cv1 * cv1;
    }
  }
#pragma unroll
  for (int off = 32; off >= 1; off >>= 1) {
    ls1 += __shfl_down(ls1, off);
    ls2 += __shfl_down(ls2, off);
    ts1 += __shfl_down(ts1, off);
    ts2 += __shfl_down(ts2, off);
  }
  if (lane == 0) { swd1[w] = ls1; swd2[w] = ls2; swv1[w] = ts1; swv2[w] = ts2; }
  __syncthreads();
  if (tid == 0) {
    float d1 = 0.0f, d2 = 0.0f, v1 = 0.0f, v2 = 0.0f;
#pragma unroll
    for (int i = 0; i < 8; ++i) { d1 += swd1[i]; d2 += swd2[i]; v1 += swv1[i]; v2 += swv2[i]; }
    part[192 + (bh * 4 + jq) * 2 + 0] = d1;
    part[192 + (bh * 4 + jq) * 2 + 1] = d2;
    if (jq == 0) { part[bh * 2] = v1; part[bh * 2 + 1] = v2; }
  }
}

// ---------------- K45: stats finalize + bn+leaky+mask+softmax (cv from ws) + AV ----------------
// 1D grid 1536, XCD-aware: reads cv/xT from the XCD that produced them. No dist recompute.
__global__ __launch_bounds__(256, 4) void k45_fused(const float* __restrict__ cvws,
    const unsigned short* __restrict__ xT, const int* __restrict__ tids,
    const float* __restrict__ part, unsigned short* __restrict__ vc16) {
  int bid = blockIdx.x;
  int xcd = bid & 7, idx = bid >> 3;
  int bh = xcd * 12 + idx % 12;            // 96 bh / 8 XCDs = 12 each
  int p = idx / 12;
  int b = bh / 6, h = bh % 6;
  int tid = threadIdx.x, w = tid >> 6, lane = tid & 63;
  int quad = lane >> 4, l16 = lane & 15;
  int I = p * 16;
  __shared__ float scv[16][257];           // staged cv tile (fp32), +1 pad
  __shared__ float svld[256];
  __shared__ unsigned short cot[16][264];
  __shared__ float smax[16][4];
  __shared__ float ssum[16][4];
  __shared__ float sstat[4];               // m, rsc, mv, rvs
  svld[tid] = (tids[b * 256 + tid] != 0) ? 1.0f : 0.0f;
  {                                        // stage 16x256 fp32 cv tile, coalesced
    int row = tid >> 4, cseg = (tid & 15) * 16;
    const float* src = cvws + ((size_t)bh * 256 + I + row) * 256 + cseg;
    float4 v0 = *(const float4*)src;
    float4 v1 = *(const float4*)(src + 4);
    float4 v2 = *(const float4*)(src + 8);
    float4 v3 = *(const float4*)(src + 12);
    *(float4*)&scv[row][cseg + 0]  = v0;
    *(float4*)&scv[row][cseg + 4]  = v1;
    *(float4*)&scv[row][cseg + 8]  = v2;
    *(float4*)&scv[row][cseg + 12] = v3;
  }
  if (w == 0) {                            // finalize BN stats from k12 partials (this h only)
    float c1 = 0.0f, c2 = 0.0f;
    {
      int bb = lane >> 2, jj = lane & 3;   // 16 b x 4 jq = 64 lanes
      c1 = part[192 + ((bb * 6 + h) * 4 + jj) * 2 + 0];
      c2 = part[192 + ((bb * 6 + h) * 4 + jj) * 2 + 1];
    }
    float v1 = 0.0f, v2 = 0.0f;
    if (lane < 16) {
      v1 = part[(lane * 6 + h) * 2 + 0];
      v2 = part[(lane * 6 + h) * 2 + 1];
    }
#pragma unroll
    for (int off = 32; off >= 1; off >>= 1) {
      c1 += __shfl_down(c1, off);
      c2 += __shfl_down(c2, off);
      v1 += __shfl_down(v1, off);
      v2 += __shfl_down(v2, off);
    }
    if (lane == 0) {
      float mean = c1 / 1048576.0f;                    // B*L*L
      float var = c2 / 1048576.0f - mean * mean;
      sstat[0] = mean;
      sstat[1] = rsqrtf(var + 1e-5f);
      float mv = v1 / 524288.0f;                       // B*L*dh
      float vv = v2 / 524288.0f - mv * mv;
      sstat[2] = mv;
      sstat[3] = rsqrtf(vv + 1e-5f);
    }
  }
  __syncthreads();
  float m = sstat[0], rsc = sstat[1];
  float rv[4];
#pragma unroll
  for (int r = 0; r < 4; ++r) rv[r] = svld[I + quad * 4 + r];
  float y[4][4];
#pragma unroll
  for (int tl = 0; tl < 4; ++tl) {
    int t = w * 4 + tl;
    float cvld = svld[t * 16 + l16];
#pragma unroll
    for (int r = 0; r < 4; ++r) {
      float cv = scv[quad * 4 + r][t * 16 + l16];
      float yv = (cv - m) * rsc;
      yv = yv >= 0.0f ? yv : 9.0f * yv;
      y[tl][r] = yv * rv[r] * cvld;
    }
  }
#pragma unroll
  for (int r = 0; r < 4; ++r) {
    float mx = fmaxf(fmaxf(y[0][r], y[1][r]), fmaxf(y[2][r], y[3][r]));
#pragma unroll
    for (int off = 1; off <= 8; off <<= 1) mx = fmaxf(mx, __shfl_xor(mx, off));
    if (l16 == 0) smax[quad * 4 + r][w] = mx;
  }
  __syncthreads();
  float gmx[4];
#pragma unroll
  for (int r = 0; r < 4; ++r) {
    int row = quad * 4 + r;
    gmx[r] = fmaxf(fmaxf(smax[row][0], smax[row][1]), fmaxf(smax[row][2], smax[row][3]));
    float s = 0.0f;
#pragma unroll
    for (int tl = 0; tl < 4; ++tl) { y[tl][r] = expf(y[tl][r] - gmx[r]); s += y[tl][r]; }
#pragma unroll
    for (int off = 1; off <= 8; off <<= 1) s += __shfl_xor(s, off);
    if (l16 == 0) ssum[row][w] = s;
  }
  __syncthreads();
#pragma unroll
  for (int r = 0; r < 4; ++r) {
    int row = quad * 4 + r;
    float gs = ssum[row][0] + ssum[row][1] + ssum[row][2] + ssum[row][3];
    float inv = 1.0f / gs;
#pragma unroll
    for (int tl = 0; tl < 4; ++tl)
      cot[row][w * 64 + tl * 16 + l16] =
          __bfloat16_as_ushort(__float2bfloat16(y[tl][r] * inv));
  }
  __syncthreads();
  bf16x8 a2[8];
#pragma unroll
  for (int k0 = 0; k0 < 8; ++k0)
    a2[k0] = *(const bf16x8*)&cot[l16][k0 * 32 + quad * 8];
  const __bf16* xbT = (const __bf16*)xT + (size_t)bh * 128 * 256;
  float mv = sstat[2], rvs = sstat[3];
  float rm = rvs * mv;
  size_t vbase = ((size_t)(b * 256 + I + quad * 4)) * 768 + h * 128;
#pragma unroll
  for (int jl = 0; jl < 2; ++jl) {
    int ch = (w * 2 + jl) * 16 + l16;
    const __bf16* brow = xbT + (size_t)ch * 256;
    f32x4 vacc = {0.0f, 0.0f, 0.0f, 0.0f};
#pragma unroll
    for (int k0 = 0; k0 < 8; ++k0) {
      bf16x8 bfr = *(const bf16x8*)(brow + k0 * 32 + quad * 8);
      vacc = __builtin_amdgcn_mfma_f32_16x16x32_bf16(a2[k0], bfr, vacc, 0, 0, 0);
    }
#pragma unroll
    for (int r = 0; r < 4; ++r) {
      float ov = rvs * vacc[r] - rm;
      vc16[vbase + (size_t)r * 768 + ch] = __bfloat16_as_ushort(__float2bfloat16(ov));
    }
  }
}

// ---------------- K5b6: logits via MFMA + 21-softmax + accumulate + last-block final softmax ----------------
// XCD-pinned so each block reads vc(b) from the XCD whose k45 blocks produced it (L2-resident).
__global__ __launch_bounds__(256) void k5b6_lgts(const unsigned short* __restrict__ vc16,
    const unsigned short* __restrict__ fcWb, const float* __restrict__ fcb,
    float* __restrict__ acc, unsigned int* __restrict__ ctr, float* __restrict__ out) {
  int bid = blockIdx.x;
  int xcd = bid & 7, idx = bid >> 3;       // 8 blocks per XCD
  int b = xcd * 2 + (idx & 1);             // matches k45's b->XCD map
  int qa = idx >> 1;
  int tid = threadIdx.x, w = tid >> 6, lane = tid & 63;
  int quad = lane >> 4, l16 = lane & 15;
  int tok0 = b * 256 + qa * 64 + w * 16;
  int c1c = (l16 < 5) ? (16 + l16) : 20;
  const __bf16* vb = (const __bf16*)vc16;
  const __bf16* w0 = (const __bf16*)fcWb + (size_t)l16 * 768;
  const __bf16* w1 = (const __bf16*)fcWb + (size_t)c1c * 768;
  f32x4 ac0 = {0.0f, 0.0f, 0.0f, 0.0f}, ac1 = {0.0f, 0.0f, 0.0f, 0.0f};
#pragma unroll
  for (int k0 = 0; k0 < 24; ++k0) {
    int ko = k0 * 32 + quad * 8;
    bf16x8 af = *(const bf16x8*)(vb + (size_t)(tok0 + l16) * 768 + ko);
    bf16x8 b0 = *(const bf16x8*)(w0 + ko);
    bf16x8 b1 = *(const bf16x8*)(w1 + ko);
    ac0 = __builtin_amdgcn_mfma_f32_16x16x32_bf16(af, b0, ac0, 0, 0, 0);
    ac1 = __builtin_amdgcn_mfma_f32_16x16x32_bf16(af, b1, ac1, 0, 0, 0);
  }
  float bias0 = fcb[l16];
  float bias1 = (l16 < 5) ? fcb[16 + l16] : 0.0f;
  float p0s = 0.0f, p1s = 0.0f;
#pragma unroll
  for (int r = 0; r < 4; ++r) {
    float lg0 = ac0[r] + bias0;
    float lg1 = (l16 < 5) ? (ac1[r] + bias1) : -1e30f;
    float mx = fmaxf(lg0, lg1);
#pragma unroll
    for (int off = 1; off <= 8; off <<= 1) mx = fmaxf(mx, __shfl_xor(mx, off));
    float e0 = expf(lg0 - mx), e1 = expf(lg1 - mx);
    float s = e0 + e1;
#pragma unroll
    for (int off = 1; off <= 8; off <<= 1) s += __shfl_xor(s, off);
    float inv = 1.0f / s;
    p0s += e0 * inv;
    p1s += e1 * inv;
  }
  p0s += __shfl_xor(p0s, 16); p0s += __shfl_xor(p0s, 32);
  p1s += __shfl_xor(p1s, 16); p1s += __shfl_xor(p1s, 32);
  __shared__ float sacc[4][21];
  __shared__ unsigned int sdone;
  if (quad == 0) sacc[w][l16] = p0s;
  if (quad == 1 && l16 < 5) sacc[w][16 + l16] = p1s;
  __syncthreads();
  if (tid < 21) {
    float s = sacc[0][tid] + sacc[1][tid] + sacc[2][tid] + sacc[3][tid];
    atomicAdd(&acc[b * 21 + tid], s);
  }
  __syncthreads();   // barrier drains vmcnt: this block's atomics are globally performed
  if (tid == 0) {
    __threadfence();
    sdone = atomicAdd(ctr, 1u);
  }
  __syncthreads();
  if (sdone == 63u && tid < 16) {
    float v[20];
    float mx = -1e30f;
#pragma unroll
    for (int c = 0; c < 20; ++c) {
      v[c] = atomicAdd(&acc[tid * 21 + c], 0.0f);   // coherent read (XCD-safe)
      mx = fmaxf(mx, v[c]);
    }
    float s = 0.0f;
#pragma unroll
    for (int c = 0; c < 20; ++c) { v[c] = expf(v[c] - mx); s += v[c]; }
    float inv = 1.0f / s;
#pragma unroll
    for (int c = 0; c < 20; ++c) out[tid * 20 + c] = v[c] * inv;
  }
}

extern "C" void kernel_launch(void* const* d_in, const int* in_sizes, int n_in,
                              void* d_out, int out_size, void* d_ws, size_t ws_size,
                              hipStream_t stream) {
  const int*   tids = (const int*)d_in[0];
  const float* TF   = (const float*)d_in[1];
  const float* DF   = (const float*)d_in[2];
  const float* emb  = (const float*)d_in[3];
  const float* fcW  = (const float*)d_in[4];
  const float* fcb  = (const float*)d_in[5];
  // d_in[6]=weiW, d_in[7]=weib: dead code (cw branch is provably all-ones)
  float* out = (float*)d_out;
  float* ws  = (float*)d_ws;
  unsigned short* xh   = (unsigned short*)(ws + OFF_XH);
  unsigned short* xT   = (unsigned short*)(ws + OFF_XT);
  unsigned short* vc   = (unsigned short*)(ws + OFF_VC);
  unsigned short* fcWb = (unsigned short*)(ws + OFF_FCWB);
  float* sq    = ws + OFF_SQ;
  float* part  = ws + OFF_PART;
  float* acc   = ws + OFF_ACC;
  float* cvws  = ws + OFF_CV;
  unsigned int* ctr = (unsigned int*)(ws + OFF_CTR);

  k12_fused<<<384, 512, 0, stream>>>(tids, TF, DF, emb, xh, xT, sq, part,
                                     fcW, fcWb, acc, ctr, cvws);
  k45_fused<<<1536, 256, 0, stream>>>(cvws, xT, tids, part, vc);
  k5b6_lgts<<<64, 256, 0, stream>>>(vc, fcWb, fcb, acc, ctr, out);
}

// Round 9
// 186.614 us; speedup vs baseline: 1.0819x; 1.0076x over previous
//
#include <hip/hip_runtime.h>
#include <hip/hip_bf16.h>
#include <math.h>

// ws layout (float slots)
#define OFF_XT   1572864UL   // bf16 x^T (bh, 128, l) token-paired u32
#define OFF_VC   3145728UL   // bf16 vc (b, l, 768)
#define OFF_SQ   4718592UL   // fp32 per-(bh,l) sumsq          (24576)
#define OFF_PART 4767744UL   // fp32 partials: [0..191] V-sum (bh:S1,S2); [192..959] dist (bh,jq:D1,D2)
#define OFF_ACC  4780056UL   // 336
#define OFF_CTR  4780392UL   // 1 uint (k5b6 completion counter)
#define OFF_FCWB 4780396UL   // bf16 fcW cast, 21*768 (8064 u16)
#define OFF_CV   8388608UL   // fp32 dist matrix (bh, i, j) 96*256*256 = 6291456 (ends at 58.7 MB)

typedef __attribute__((ext_vector_type(8))) __bf16 bf16x8;
typedef __attribute__((ext_vector_type(4))) float f32x4;
typedef __attribute__((ext_vector_type(8))) unsigned short u16x8;

// ---------------- K12: gather -> LDS tile (+xT, sq) + dist (stored fp32) + BN partials ----------------
// 1D grid 384, XCD-pinned: xcd=bid&7, bh=xcd*12+idx%12, jq=idx/12 (4 col-quarters per bh).
// cv computed ONCE here and stored; k45 reads it (bit-identical). xh removed (dead).
__global__ __launch_bounds__(512) void k12_fused(const int* __restrict__ tids,
    const float* __restrict__ TF, const float* __restrict__ DF,
    const float* __restrict__ emb, unsigned short* __restrict__ xT,
    float* __restrict__ sq, float* __restrict__ part, const float* __restrict__ fcW,
    unsigned short* __restrict__ fcWb, float* __restrict__ acc,
    unsigned int* __restrict__ ctr, float* __restrict__ cvws) {
  int bid = blockIdx.x;
  int xcd = bid & 7, idx = bid >> 3;       // 48 blocks per XCD
  int bh = xcd * 12 + idx % 12;            // same bh->XCD map as k45 (L2 handoff)
  int jq = idx / 12;                       // 0..3: dist col-quarter
  int b = bh / 6, h = bh % 6;
  int tid = threadIdx.x;
  __shared__ unsigned short tile[32768];   // 64 KiB
  __shared__ float swd1[8], swd2[8], swv1[8], swv2[8];
  if (jq == 1) {                           // fcW -> bf16 cast, partitioned over 96 blocks
    if (tid < 168) {
      int i2 = bh * 168 + tid;
      fcWb[i2] = __bfloat16_as_ushort(__float2bfloat16(fcW[i2]));
    }
  } else if (jq == 0 && bh == 0) {         // zero acc + k5b6 counter (2 launches ahead)
    if (tid < 336) acc[tid] = 0.0f;
    if (tid == 336) *ctr = 0u;
  }
  int sub = tid & 7, row0 = tid >> 3;      // 8 threads per token row
  int c16 = sub * 16;
  float ts1 = 0.0f, ts2 = 0.0f;            // per-thread V-sum partials
#pragma unroll
  for (int p = 0; p < 4; ++p) {
    int r = p * 64 + row0;
    int tok = b * 256 + r;
    int tv = tids[tok];
    float wgt = fminf(TF[tok], 20.0f) * log1pf(1.0f / DF[tok]);
    const float* er = emb + (size_t)tv * 768 + h * 128 + c16;
    float4 e0 = *(const float4*)er;
    float4 e1 = *(const float4*)(er + 4);
    float4 e2 = *(const float4*)(er + 8);
    float4 e3 = *(const float4*)(er + 12);
    float f[16] = {e0.x, e0.y, e0.z, e0.w, e1.x, e1.y, e1.z, e1.w,
                   e2.x, e2.y, e2.z, e2.w, e3.x, e3.y, e3.z, e3.w};
    u16x8 pk0, pk1;
    float s1 = 0.0f, s2 = 0.0f;
#pragma unroll
    for (int e = 0; e < 8; ++e) {
      __hip_bfloat16 hb = __float2bfloat16(f[e] * wgt);
      float g = __bfloat162float(hb);
      s1 += g; s2 += g * g;
      pk0[e] = __bfloat16_as_ushort(hb);
    }
#pragma unroll
    for (int e = 0; e < 8; ++e) {
      __hip_bfloat16 hb = __float2bfloat16(f[8 + e] * wgt);
      float g = __bfloat162float(hb);
      s1 += g; s2 += g * g;
      pk1[e] = __bfloat16_as_ushort(hb);
    }
    ts1 += s1; ts2 += s2;
    int rx = r & 7;
    *(u16x8*)&tile[r * 128 + (((sub * 2    ) ^ rx) * 8)] = pk0;
    *(u16x8*)&tile[r * 128 + (((sub * 2 + 1) ^ rx) * 8)] = pk1;
    s2 += __shfl_down(s2, 4); s2 += __shfl_down(s2, 2); s2 += __shfl_down(s2, 1);
    if (sub == 0)
      sq[(size_t)bh * 256 + r] = s2;       // all 4 jq blocks write identical values (benign)
  }
  __syncthreads();
  // jq==3 block emits the channel-major transpose xT (token-paired u32) from LDS
  if (jq == 3) {
    int ch = tid & 127, q = tid >> 7;          // 4 token-quarters
    int cc = ch >> 3, cs = ch & 7;
    unsigned int* xo = (unsigned int*)xT + ((size_t)bh * 128 + ch) * 128 + q * 32;
#pragma unroll
    for (int g = 0; g < 8; ++g) {
      unsigned int tmp[4];
#pragma unroll
      for (int k = 0; k < 4; ++k) {
        int t0 = q * 64 + (g * 4 + k) * 2;
        unsigned int lo = tile[ t0      * 128 + ((cc ^ ( t0      & 7)) * 8) + cs];
        unsigned int hi = tile[(t0 + 1) * 128 + ((cc ^ ((t0 + 1) & 7)) * 8) + cs];
        tmp[k] = lo | (hi << 16);
      }
      uint4 vv; vv.x = tmp[0]; vv.y = tmp[1]; vv.z = tmp[2]; vv.w = tmp[3];
      *(uint4*)(xo + g * 4) = vv;
    }
  }
  // dist: wave w -> i-tiles {2w,2w+1}, cols [64*jq, 64*jq+64); store cv fp32 + BN partials
  int w = tid >> 6, lane = tid & 63, quad = lane >> 4, l16 = lane & 15;
  const float* sqh = sq + (size_t)bh * 256;
  int it0 = w * 2;
  bf16x8 a2[2][4];
  float si2[2][4];
#pragma unroll
  for (int ith = 0; ith < 2; ++ith) {
    int ar = (it0 + ith) * 16 + l16, arx = ar & 7;
#pragma unroll
    for (int k0 = 0; k0 < 4; ++k0)
      a2[ith][k0] = *(const bf16x8*)&tile[ar * 128 + (((k0 * 4 + quad) ^ arx) * 8)];
#pragma unroll
    for (int r = 0; r < 4; ++r)
      si2[ith][r] = sqh[(it0 + ith) * 16 + quad * 4 + r];
  }
  float ls1 = 0.0f, ls2 = 0.0f;
#pragma unroll
  for (int jt = 0; jt < 4; ++jt) {
    int jcol = jq * 64 + jt * 16 + l16;
    int jrx = jcol & 7;
    bf16x8 bfr[4];
#pragma unroll
    for (int k0 = 0; k0 < 4; ++k0)
      bfr[k0] = *(const bf16x8*)&tile[jcol * 128 + (((k0 * 4 + quad) ^ jrx) * 8)];
    f32x4 acc0 = {0.0f, 0.0f, 0.0f, 0.0f}, acc1 = {0.0f, 0.0f, 0.0f, 0.0f};
#pragma unroll
    for (int k0 = 0; k0 < 4; ++k0) {
      acc0 = __builtin_amdgcn_mfma_f32_16x16x32_bf16(a2[0][k0], bfr[k0], acc0, 0, 0, 0);
      acc1 = __builtin_amdgcn_mfma_f32_16x16x32_bf16(a2[1][k0], bfr[k0], acc1, 0, 0, 0);
    }
    float sj = sqh[jcol];
#pragma unroll
    for (int r = 0; r < 4; ++r) {
      float cv0 = sqrtf(fmaxf(si2[0][r] + sj - 2.0f * acc0[r], 1e-12f));
      float cv1 = sqrtf(fmaxf(si2[1][r] + sj - 2.0f * acc1[r], 1e-12f));
      cvws[((size_t)bh * 256 + (it0    ) * 16 + quad * 4 + r) * 256 + jcol] = cv0;
      cvws[((size_t)bh * 256 + (it0 + 1) * 16 + quad * 4 + r) * 256 + jcol] = cv1;
      ls1 += cv0 + cv1;
      ls2 += cv0 * cv0 + cv1 * cv1;
    }
  }
#pragma unroll
  for (int off = 32; off >= 1; off >>= 1) {
    ls1 += __shfl_down(ls1, off);
    ls2 += __shfl_down(ls2, off);
    ts1 += __shfl_down(ts1, off);
    ts2 += __shfl_down(ts2, off);
  }
  if (lane == 0) { swd1[w] = ls1; swd2[w] = ls2; swv1[w] = ts1; swv2[w] = ts2; }
  __syncthreads();
  if (tid == 0) {
    float d1 = 0.0f, d2 = 0.0f, v1 = 0.0f, v2 = 0.0f;
#pragma unroll
    for (int i = 0; i < 8; ++i) { d1 += swd1[i]; d2 += swd2[i]; v1 += swv1[i]; v2 += swv2[i]; }
    part[192 + (bh * 4 + jq) * 2 + 0] = d1;
    part[192 + (bh * 4 + jq) * 2 + 1] = d2;
    if (jq == 0) { part[bh * 2] = v1; part[bh * 2 + 1] = v2; }
  }
}

// ---------------- K45: stats finalize + bn+leaky+mask+softmax (cv from ws) + AV ----------------
// No VGPR cap (launch_bounds 256 only); vc written via LDS restage -> one u16x8/thread, coalesced.
__global__ __launch_bounds__(256) void k45_fused(const float* __restrict__ cvws,
    const unsigned short* __restrict__ xT, const int* __restrict__ tids,
    const float* __restrict__ part, unsigned short* __restrict__ vc16) {
  int bid = blockIdx.x;
  int xcd = bid & 7, idx = bid >> 3;
  int bh = xcd * 12 + idx % 12;            // 96 bh / 8 XCDs = 12 each
  int p = idx / 12;
  int b = bh / 6, h = bh % 6;
  int tid = threadIdx.x, w = tid >> 6, lane = tid & 63;
  int quad = lane >> 4, l16 = lane & 15;
  int I = p * 16;
  __shared__ float scv[16][257];           // staged cv tile (fp32), +1 pad
  __shared__ float svld[256];
  __shared__ unsigned short cot[16][264];  // co tile; reused as vc restage buffer (vt)
  __shared__ float smax[16][4];
  __shared__ float ssum[16][4];
  __shared__ float sstat[4];               // m, rsc, mv, rvs
  svld[tid] = (tids[b * 256 + tid] != 0) ? 1.0f : 0.0f;
  {                                        // stage 16x256 fp32 cv tile, coalesced
    int row = tid >> 4, cseg = (tid & 15) * 16;
    const float* src = cvws + ((size_t)bh * 256 + I + row) * 256 + cseg;
    float4 v0 = *(const float4*)src;
    float4 v1 = *(const float4*)(src + 4);
    float4 v2 = *(const float4*)(src + 8);
    float4 v3 = *(const float4*)(src + 12);
    *(float4*)&scv[row][cseg + 0]  = v0;
    *(float4*)&scv[row][cseg + 4]  = v1;
    *(float4*)&scv[row][cseg + 8]  = v2;
    *(float4*)&scv[row][cseg + 12] = v3;
  }
  if (w == 0) {                            // finalize BN stats from k12 partials (this h only)
    float c1 = 0.0f, c2 = 0.0f;
    {
      int bb = lane >> 2, jj = lane & 3;   // 16 b x 4 jq = 64 lanes
      c1 = part[192 + ((bb * 6 + h) * 4 + jj) * 2 + 0];
      c2 = part[192 + ((bb * 6 + h) * 4 + jj) * 2 + 1];
    }
    float v1 = 0.0f, v2 = 0.0f;
    if (lane < 16) {
      v1 = part[(lane * 6 + h) * 2 + 0];
      v2 = part[(lane * 6 + h) * 2 + 1];
    }
#pragma unroll
    for (int off = 32; off >= 1; off >>= 1) {
      c1 += __shfl_down(c1, off);
      c2 += __shfl_down(c2, off);
      v1 += __shfl_down(v1, off);
      v2 += __shfl_down(v2, off);
    }
    if (lane == 0) {
      float mean = c1 / 1048576.0f;                    // B*L*L
      float var = c2 / 1048576.0f - mean * mean;
      sstat[0] = mean;
      sstat[1] = rsqrtf(var + 1e-5f);
      float mv = v1 / 524288.0f;                       // B*L*dh
      float vv = v2 / 524288.0f - mv * mv;
      sstat[2] = mv;
      sstat[3] = rsqrtf(vv + 1e-5f);
    }
  }
  __syncthreads();
  float m = sstat[0], rsc = sstat[1];
  float rv[4];
#pragma unroll
  for (int r = 0; r < 4; ++r) rv[r] = svld[I + quad * 4 + r];
  float y[4][4];
#pragma unroll
  for (int tl = 0; tl < 4; ++tl) {
    int t = w * 4 + tl;
    float cvld = svld[t * 16 + l16];
#pragma unroll
    for (int r = 0; r < 4; ++r) {
      float cv = scv[quad * 4 + r][t * 16 + l16];
      float yv = (cv - m) * rsc;
      yv = yv >= 0.0f ? yv : 9.0f * yv;
      y[tl][r] = yv * rv[r] * cvld;
    }
  }
#pragma unroll
  for (int r = 0; r < 4; ++r) {
    float mx = fmaxf(fmaxf(y[0][r], y[1][r]), fmaxf(y[2][r], y[3][r]));
#pragma unroll
    for (int off = 1; off <= 8; off <<= 1) mx = fmaxf(mx, __shfl_xor(mx, off));
    if (l16 == 0) smax[quad * 4 + r][w] = mx;
  }
  __syncthreads();
  float gmx[4];
#pragma unroll
  for (int r = 0; r < 4; ++r) {
    int row = quad * 4 + r;
    gmx[r] = fmaxf(fmaxf(smax[row][0], smax[row][1]), fmaxf(smax[row][2], smax[row][3]));
    float s = 0.0f;
#pragma unroll
    for (int tl = 0; tl < 4; ++tl) { y[tl][r] = expf(y[tl][r] - gmx[r]); s += y[tl][r]; }
#pragma unroll
    for (int off = 1; off <= 8; off <<= 1) s += __shfl_xor(s, off);
    if (l16 == 0) ssum[row][w] = s;
  }
  __syncthreads();
#pragma unroll
  for (int r = 0; r < 4; ++r) {
    int row = quad * 4 + r;
    float gs = ssum[row][0] + ssum[row][1] + ssum[row][2] + ssum[row][3];
    float inv = 1.0f / gs;
#pragma unroll
    for (int tl = 0; tl < 4; ++tl)
      cot[row][w * 64 + tl * 16 + l16] =
          __bfloat16_as_ushort(__float2bfloat16(y[tl][r] * inv));
  }
  __syncthreads();
  bf16x8 a2[8];
#pragma unroll
  for (int k0 = 0; k0 < 8; ++k0)
    a2[k0] = *(const bf16x8*)&cot[l16][k0 * 32 + quad * 8];
  __syncthreads();                         // cot fragments now in regs; reuse cot as vt
  const __bf16* xbT = (const __bf16*)xT + (size_t)bh * 128 * 256;
  float mv = sstat[2], rvs = sstat[3];
  float rm = rvs * mv;
#pragma unroll
  for (int jl = 0; jl < 2; ++jl) {
    int ch = (w * 2 + jl) * 16 + l16;
    const __bf16* brow = xbT + (size_t)ch * 256;
    f32x4 vacc = {0.0f, 0.0f, 0.0f, 0.0f};
#pragma unroll
    for (int k0 = 0; k0 < 8; ++k0) {
      bf16x8 bfr = *(const bf16x8*)(brow + k0 * 32 + quad * 8);
      vacc = __builtin_amdgcn_mfma_f32_16x16x32_bf16(a2[k0], bfr, vacc, 0, 0, 0);
    }
#pragma unroll
    for (int r = 0; r < 4; ++r) {
      float ov = rvs * vacc[r] - rm;
      cot[quad * 4 + r][ch] = __bfloat16_as_ushort(__float2bfloat16(ov));   // vt stage
    }
  }
  __syncthreads();
  {                                        // coalesced vc store: 1 u16x8 per thread
    int row = tid >> 4, seg = (tid & 15) * 8;
    u16x8 pkv = *(const u16x8*)&cot[row][seg];
    *(u16x8*)(vc16 + ((size_t)(b * 256 + I + row)) * 768 + h * 128 + seg) = pkv;
  }
}

// ---------------- K5b6: logits via MFMA + 21-softmax + accumulate + last-block final softmax ----------------
__global__ __launch_bounds__(256) void k5b6_lgts(const unsigned short* __restrict__ vc16,
    const unsigned short* __restrict__ fcWb, const float* __restrict__ fcb,
    float* __restrict__ acc, unsigned int* __restrict__ ctr, float* __restrict__ out) {
  int bid = blockIdx.x;
  int xcd = bid & 7, idx = bid >> 3;       // 8 blocks per XCD
  int b = xcd * 2 + (idx & 1);             // matches k45's b->XCD map
  int qa = idx >> 1;
  int tid = threadIdx.x, w = tid >> 6, lane = tid & 63;
  int quad = lane >> 4, l16 = lane & 15;
  int tok0 = b * 256 + qa * 64 + w * 16;
  int c1c = (l16 < 5) ? (16 + l16) : 20;
  const __bf16* vb = (const __bf16*)vc16;
  const __bf16* w0 = (const __bf16*)fcWb + (size_t)l16 * 768;
  const __bf16* w1 = (const __bf16*)fcWb + (size_t)c1c * 768;
  f32x4 ac0 = {0.0f, 0.0f, 0.0f, 0.0f}, ac1 = {0.0f, 0.0f, 0.0f, 0.0f};
#pragma unroll
  for (int k0 = 0; k0 < 24; ++k0) {
    int ko = k0 * 32 + quad * 8;
    bf16x8 af = *(const bf16x8*)(vb + (size_t)(tok0 + l16) * 768 + ko);
    bf16x8 b0 = *(const bf16x8*)(w0 + ko);
    bf16x8 b1 = *(const bf16x8*)(w1 + ko);
    ac0 = __builtin_amdgcn_mfma_f32_16x16x32_bf16(af, b0, ac0, 0, 0, 0);
    ac1 = __builtin_amdgcn_mfma_f32_16x16x32_bf16(af, b1, ac1, 0, 0, 0);
  }
  float bias0 = fcb[l16];
  float bias1 = (l16 < 5) ? fcb[16 + l16] : 0.0f;
  float p0s = 0.0f, p1s = 0.0f;
#pragma unroll
  for (int r = 0; r < 4; ++r) {
    float lg0 = ac0[r] + bias0;
    float lg1 = (l16 < 5) ? (ac1[r] + bias1) : -1e30f;
    float mx = fmaxf(lg0, lg1);
#pragma unroll
    for (int off = 1; off <= 8; off <<= 1) mx = fmaxf(mx, __shfl_xor(mx, off));
    float e0 = expf(lg0 - mx), e1 = expf(lg1 - mx);
    float s = e0 + e1;
#pragma unroll
    for (int off = 1; off <= 8; off <<= 1) s += __shfl_xor(s, off);
    float inv = 1.0f / s;
    p0s += e0 * inv;
    p1s += e1 * inv;
  }
  p0s += __shfl_xor(p0s, 16); p0s += __shfl_xor(p0s, 32);
  p1s += __shfl_xor(p1s, 16); p1s += __shfl_xor(p1s, 32);
  __shared__ float sacc[4][21];
  __shared__ unsigned int sdone;
  if (quad == 0) sacc[w][l16] = p0s;
  if (quad == 1 && l16 < 5) sacc[w][16 + l16] = p1s;
  __syncthreads();
  if (tid < 21) {
    float s = sacc[0][tid] + sacc[1][tid] + sacc[2][tid] + sacc[3][tid];
    atomicAdd(&acc[b * 21 + tid], s);
  }
  __syncthreads();   // barrier drains vmcnt: this block's atomics are globally performed
  if (tid == 0) {
    __threadfence();
    sdone = atomicAdd(ctr, 1u);
  }
  __syncthreads();
  if (sdone == 63u && tid < 16) {
    float v[20];
    float mx = -1e30f;
#pragma unroll
    for (int c = 0; c < 20; ++c) {
      v[c] = atomicAdd(&acc[tid * 21 + c], 0.0f);   // coherent read (XCD-safe)
      mx = fmaxf(mx, v[c]);
    }
    float s = 0.0f;
#pragma unroll
    for (int c = 0; c < 20; ++c) { v[c] = expf(v[c] - mx); s += v[c]; }
    float inv = 1.0f / s;
#pragma unroll
    for (int c = 0; c < 20; ++c) out[tid * 20 + c] = v[c] * inv;
  }
}

extern "C" void kernel_launch(void* const* d_in, const int* in_sizes, int n_in,
                              void* d_out, int out_size, void* d_ws, size_t ws_size,
                              hipStream_t stream) {
  const int*   tids = (const int*)d_in[0];
  const float* TF   = (const float*)d_in[1];
  const float* DF   = (const float*)d_in[2];
  const float* emb  = (const float*)d_in[3];
  const float* fcW  = (const float*)d_in[4];
  const float* fcb  = (const float*)d_in[5];
  // d_in[6]=weiW, d_in[7]=weib: dead code (cw branch is provably all-ones)
  float* out = (float*)d_out;
  float* ws  = (float*)d_ws;
  unsigned short* xT   = (unsigned short*)(ws + OFF_XT);
  unsigned short* vc   = (unsigned short*)(ws + OFF_VC);
  unsigned short* fcWb = (unsigned short*)(ws + OFF_FCWB);
  float* sq    = ws + OFF_SQ;
  float* part  = ws + OFF_PART;
  float* acc   = ws + OFF_ACC;
  float* cvws  = ws + OFF_CV;
  unsigned int* ctr = (unsigned int*)(ws + OFF_CTR);

  k12_fused<<<384, 512, 0, stream>>>(tids, TF, DF, emb, xT, sq, part,
                                     fcW, fcWb, acc, ctr, cvws);
  k45_fused<<<1536, 256, 0, stream>>>(cvws, xT, tids, part, vc);
  k5b6_lgts<<<64, 256, 0, stream>>>(vc, fcWb, fcb, acc, ctr, out);
}